// Round 1
// baseline (534.362 us; speedup 1.0000x reference)
//
#include <hip/hip_runtime.h>
#include <stdint.h>

#define HID 1024
#define SEQ 2048
#define NB 2
#define NH 16
#define HD 64
#define MROWS 4096  // NB*SEQ

typedef float f32x4 __attribute__((ext_vector_type(4)));
typedef short s16x4 __attribute__((ext_vector_type(4)));
typedef short s16x8 __attribute__((ext_vector_type(8)));

#define MFMA16(a, b, c) __builtin_amdgcn_mfma_f32_16x16x32_bf16((a), (b), (c), 0, 0, 0)

#define GLOAD_LDS16(gp, lp)                                                    \
  __builtin_amdgcn_global_load_lds(                                            \
      (const __attribute__((address_space(1))) unsigned int*)(gp),             \
      (__attribute__((address_space(3))) unsigned int*)(lp), 16, 0, 0)

__device__ __forceinline__ short f2bf(float x) {
  uint32_t u = __builtin_bit_cast(uint32_t, x);
  u += 0x7fffu + ((u >> 16) & 1u);
  return (short)(u >> 16);
}

// ---------------- cast X: f32 -> bf16, 8 elems/thread ----------------
__global__ __launch_bounds__(256) void cast_x_kernel(const float* __restrict__ src,
                                                     short* __restrict__ dst) {
  const size_t i = (size_t)blockIdx.x * 256 + threadIdx.x;
  const float* s = src + i * 8;
  f32x4 a = *(const f32x4*)(s);
  f32x4 b = *(const f32x4*)(s + 4);
  s16x8 o;
  o[0] = f2bf(a[0]); o[1] = f2bf(a[1]); o[2] = f2bf(a[2]); o[3] = f2bf(a[3]);
  o[4] = f2bf(b[0]); o[5] = f2bf(b[1]); o[6] = f2bf(b[2]); o[7] = f2bf(b[3]);
  *(s16x8*)(dst + i * 8) = o;
}

// ------ transpose-cast: W[k][n] f32 -> Wt[n][k] bf16 (1024x1024) ------
__global__ __launch_bounds__(256) void transpose_cast_kernel(const float* __restrict__ src,
                                                             short* __restrict__ dst) {
  __shared__ float t[32][33];
  const int tx = threadIdx.x & 31, ty = threadIdx.x >> 5;
  const int r0 = blockIdx.y * 32, c0 = blockIdx.x * 32;
#pragma unroll
  for (int i = 0; i < 4; i++)
    t[ty + i * 8][tx] = src[(size_t)(r0 + ty + i * 8) * HID + c0 + tx];
  __syncthreads();
#pragma unroll
  for (int i = 0; i < 4; i++)
    dst[(size_t)(c0 + ty + i * 8) * HID + r0 + tx] = f2bf(t[tx][ty + i * 8]);
}

// ---------------- bf16 GEMM: C = A[M][1024] * Bt[N][1024]^T ----------------
// 128x128 tile, BK=32, 4 waves (2x2), 16x16x32 MFMA, global_load_lds staging.
// EPI 0: QKV epilogue (bias + scatter to Qb/Kb [bh][s][d], Vt [bh][d][s], bf16)
// EPI 1: proj epilogue (bias + f32 out [m][1024])
template <int EPI>
__global__ __launch_bounds__(256) void gemm_bf16(
    const short* __restrict__ A, const short* __restrict__ Bt,
    const float* __restrict__ b0, const float* __restrict__ b1,
    const float* __restrict__ b2, short* __restrict__ Qb, short* __restrict__ Kb,
    short* __restrict__ Vt, float* __restrict__ Out) {
  __shared__ char lds[16384];  // A tile [128][32] @0, B tile [128][32] @8192
  const int tid = threadIdx.x;
  const int w = tid >> 6, l = tid & 63, lg = l >> 4, ln = l & 15;
  const int wm = w >> 1, wn = w & 1;
  const int m0 = blockIdx.y * 128, n0 = blockIdx.x * 128;

  f32x4 acc[4][4];
#pragma unroll
  for (int i = 0; i < 4; i++)
#pragma unroll
    for (int j = 0; j < 4; j++) acc[i][j] = f32x4{0.f, 0.f, 0.f, 0.f};

  for (int k0 = 0; k0 < 1024; k0 += 32) {
    __syncthreads();  // protect LDS from prior-iter readers
#pragma unroll
    for (int i = 0; i < 2; i++) {
      const int chunk = (w * 2 + i) * 64 + l;  // 16B chunk id, 4 chunks/row
      const int row = chunk >> 2;
      const int cs = (chunk & 3) ^ (row & 3);  // source-side XOR swizzle
      GLOAD_LDS16(A + (size_t)(m0 + row) * 1024 + k0 + cs * 8,
                  lds + (w * 2 + i) * 1024);
      GLOAD_LDS16(Bt + (size_t)(n0 + row) * 1024 + k0 + cs * 8,
                  lds + 8192 + (w * 2 + i) * 1024);
    }
    __syncthreads();  // compiler emits vmcnt(0) before barrier

    s16x8 af[4], bfr[4];
#pragma unroll
    for (int mi = 0; mi < 4; mi++) {
      const int row = wm * 64 + mi * 16 + ln;
      af[mi] = *(const s16x8*)(lds + row * 64 + ((lg ^ (row & 3)) * 16));
    }
#pragma unroll
    for (int ni = 0; ni < 4; ni++) {
      const int row = wn * 64 + ni * 16 + ln;
      bfr[ni] = *(const s16x8*)(lds + 8192 + row * 64 + ((lg ^ (row & 3)) * 16));
    }
#pragma unroll
    for (int mi = 0; mi < 4; mi++)
#pragma unroll
      for (int ni = 0; ni < 4; ni++)
        acc[mi][ni] = MFMA16(af[mi], bfr[ni], acc[mi][ni]);
  }

  // epilogue: C/D layout row=(lane>>4)*4+reg, col=lane&15
#pragma unroll
  for (int ni = 0; ni < 4; ni++) {
    const int c = n0 + wn * 64 + ni * 16 + ln;
    if (EPI == 0) {
      const int mat = c >> 10, cc = c & 1023, hh = cc >> 6, d = cc & 63;
      const float* bp = (mat == 0) ? b0 : (mat == 1) ? b1 : b2;
      const float bias = bp[cc];
#pragma unroll
      for (int mi = 0; mi < 4; mi++) {
#pragma unroll
        for (int r = 0; r < 4; r++) {
          const int m = m0 + wm * 64 + mi * 16 + lg * 4 + r;
          const int bb = m >> 11, s = m & 2047;
          const short v = f2bf(acc[mi][ni][r] + bias);
          const size_t bh = (size_t)(bb * 16 + hh);
          if (mat == 0)
            Qb[(bh * SEQ + s) * HD + d] = v;
          else if (mat == 1)
            Kb[(bh * SEQ + s) * HD + d] = v;
          else
            Vt[(bh * HD + d) * SEQ + s] = v;
        }
      }
    } else {
      const float bias = b0[c];
#pragma unroll
      for (int mi = 0; mi < 4; mi++)
#pragma unroll
        for (int r = 0; r < 4; r++) {
          const int m = m0 + wm * 64 + mi * 16 + lg * 4 + r;
          Out[(size_t)m * 1024 + c] = acc[mi][ni][r] + bias;
        }
    }
  }
}

// ---------------- flash attention (causal), LDS-free ----------------
// grid (qt=32, bh=32), 256 thr = 4 waves, each wave owns 16 query rows.
// S^T = mfma(K, Q): lane owns query column q = l&15; softmax state is
// per-lane scalar; P feeds PV B-operand with no cross-lane movement.
__global__ __launch_bounds__(256) void attn_kernel(const short* __restrict__ Qb,
                                                   const short* __restrict__ Kb,
                                                   const short* __restrict__ Vt,
                                                   short* __restrict__ Ob) {
  const int qt = blockIdx.x, bh = blockIdx.y;
  const int tid = threadIdx.x;
  const int w = tid >> 6, l = tid & 63, lg = l >> 4, ln = l & 15;
  const int q0 = qt * 64;
  const int qrow = q0 + w * 16 + ln;

  const short* Qp = Qb + ((size_t)bh * SEQ + qrow) * HD;
  const s16x8 qf0 = *(const s16x8*)(Qp + lg * 8);
  const s16x8 qf1 = *(const s16x8*)(Qp + 32 + lg * 8);

  const short* Kbase = Kb + (size_t)bh * (SEQ * HD);
  const short* Vbase = Vt + (size_t)bh * (HD * SEQ);

  float m_run = -1e30f, l_run = 0.f;
  f32x4 o[4];
#pragma unroll
  for (int i = 0; i < 4; i++) o[i] = f32x4{0.f, 0.f, 0.f, 0.f};

  for (int kt = 0; kt <= qt; ++kt) {
    const int k0 = kt * 64;
    // ---- QK^T (S^T tile: 64 keys x 16 queries per wave) ----
    f32x4 st[4];
#pragma unroll
    for (int mt = 0; mt < 4; mt++) st[mt] = f32x4{0.f, 0.f, 0.f, 0.f};
#pragma unroll
    for (int mt = 0; mt < 4; mt++) {
      const short* Kp = Kbase + (size_t)(k0 + mt * 16 + ln) * HD + lg * 8;
      const s16x8 kf0 = *(const s16x8*)(Kp);
      const s16x8 kf1 = *(const s16x8*)(Kp + 32);
      st[mt] = MFMA16(kf0, qf0, st[mt]);
      st[mt] = MFMA16(kf1, qf1, st[mt]);
    }
    // ---- scale + causal mask + online softmax ----
    float p[4][4];
    float pmax = -1e30f;
#pragma unroll
    for (int mt = 0; mt < 4; mt++)
#pragma unroll
      for (int r = 0; r < 4; r++) {
        float v = st[mt][r] * 0.125f;  // 1/sqrt(64)
        const int key = k0 + mt * 16 + lg * 4 + r;
        if (key > qrow) v = -1e30f;
        p[mt][r] = v;
        pmax = fmaxf(pmax, v);
      }
    pmax = fmaxf(pmax, __shfl_xor(pmax, 16));
    pmax = fmaxf(pmax, __shfl_xor(pmax, 32));
    const float m_new = fmaxf(m_run, pmax);
    const float corr = __expf(m_run - m_new);
    float psum = 0.f;
#pragma unroll
    for (int mt = 0; mt < 4; mt++)
#pragma unroll
      for (int r = 0; r < 4; r++) {
        const float e = __expf(p[mt][r] - m_new);
        p[mt][r] = e;
        psum += e;
      }
    psum += __shfl_xor(psum, 16);
    psum += __shfl_xor(psum, 32);
    l_run = l_run * corr + psum;
    m_run = m_new;
#pragma unroll
    for (int i = 0; i < 4; i++) o[i] *= corr;

    // ---- pack P -> bf16 B-frags (kappa: key = k0+s*32+h*16+lg*4+r) ----
    s16x8 pf[2];
#pragma unroll
    for (int s = 0; s < 2; s++)
#pragma unroll
      for (int h = 0; h < 2; h++)
#pragma unroll
        for (int r = 0; r < 4; r++) pf[s][h * 4 + r] = f2bf(p[s * 2 + h][r]);

    // ---- PV: O^T[d][q] += V^T[d][k] * P[k][q] ----
#pragma unroll
    for (int s = 0; s < 2; s++)
#pragma unroll
      for (int vmt = 0; vmt < 4; vmt++) {
        const short* Vp =
            Vbase + (size_t)(vmt * 16 + ln) * SEQ + k0 + s * 32 + lg * 4;
        const s16x4 v0 = *(const s16x4*)(Vp);
        const s16x4 v1 = *(const s16x4*)(Vp + 16);
        const s16x8 vf = __builtin_shufflevector(v0, v1, 0, 1, 2, 3, 4, 5, 6, 7);
        o[vmt] = MFMA16(vf, pf[s], o[vmt]);
      }
  }

  // ---- epilogue: lane holds O^T[d][q=ln] for 16 d values, one q row ----
  const float inv = 1.0f / l_run;
  const int bb = bh >> 4, hh = bh & 15;
  const size_t orow = (size_t)(bb * SEQ + qrow) * HID + hh * HD;
#pragma unroll
  for (int mt = 0; mt < 4; mt++) {
    s16x4 ov;
#pragma unroll
    for (int r = 0; r < 4; r++) ov[r] = f2bf(o[mt][r] * inv);
    *(s16x4*)(Ob + orow + mt * 16 + lg * 4) = ov;
  }
}

// ---------------- launch ----------------
extern "C" void kernel_launch(void* const* d_in, const int* in_sizes, int n_in,
                              void* d_out, int out_size, void* d_ws,
                              size_t ws_size, hipStream_t stream) {
  const float* X = (const float*)d_in[0];
  // d_in[1] = mask (causal, implemented directly)
  const float* Wq = (const float*)d_in[2];
  const float* bq = (const float*)d_in[3];
  const float* Wk = (const float*)d_in[4];
  const float* bk = (const float*)d_in[5];
  const float* Wv = (const float*)d_in[6];
  const float* bv = (const float*)d_in[7];
  const float* Wo = (const float*)d_in[8];
  const float* bo = (const float*)d_in[9];
  float* out = (float*)d_out;

  char* ws = (char*)d_ws;
  short* Xb = (short*)(ws);                    // 8 MB  [4096][1024]
  short* Wt = (short*)(ws + (8u << 20));       // 6 MB  [3072][1024] (Wq|Wk|Wv)^T
  short* Wto = (short*)(ws + (14u << 20));     // 2 MB  [1024][1024] Wo^T
  short* Qb = (short*)(ws + (16u << 20));      // 8 MB  [32][2048][64]
  short* Kb = (short*)(ws + (24u << 20));      // 8 MB
  short* Vt = (short*)(ws + (32u << 20));      // 8 MB  [32][64][2048]
  short* Ob = (short*)(ws + (40u << 20));      // 8 MB  [4096][1024]

  cast_x_kernel<<<2048, 256, 0, stream>>>(X, Xb);
  transpose_cast_kernel<<<dim3(32, 32), 256, 0, stream>>>(Wq, Wt);
  transpose_cast_kernel<<<dim3(32, 32), 256, 0, stream>>>(Wk, Wt + (1u << 20));
  transpose_cast_kernel<<<dim3(32, 32), 256, 0, stream>>>(Wv, Wt + (2u << 20));
  transpose_cast_kernel<<<dim3(32, 32), 256, 0, stream>>>(Wo, Wto);

  gemm_bf16<0><<<dim3(24, 32), 256, 0, stream>>>(Xb, Wt, bq, bk, bv, Qb, Kb, Vt,
                                                 nullptr);
  attn_kernel<<<dim3(32, 32), 256, 0, stream>>>(Qb, Kb, Vt, Ob);
  gemm_bf16<1><<<dim3(8, 32), 256, 0, stream>>>(Ob, Wto, bo, nullptr, nullptr,
                                                nullptr, nullptr, nullptr, out);
}

// Round 3
// 296.172 us; speedup vs baseline: 1.8042x; 1.8042x over previous
//
#include <hip/hip_runtime.h>
#include <stdint.h>

#define HID 1024
#define SEQ 2048
#define NB 2
#define NH 16
#define HD 64
#define MROWS 4096  // NB*SEQ

typedef float f32x4 __attribute__((ext_vector_type(4)));
typedef short s16x4 __attribute__((ext_vector_type(4)));
typedef short s16x8 __attribute__((ext_vector_type(8)));

#define MFMA16(a, b, c) __builtin_amdgcn_mfma_f32_16x16x32_bf16((a), (b), (c), 0, 0, 0)

#define GLOAD_LDS16(gp, lp)                                                    \
  __builtin_amdgcn_global_load_lds(                                            \
      (const __attribute__((address_space(1))) unsigned int*)(gp),             \
      (__attribute__((address_space(3))) unsigned int*)(lp), 16, 0, 0)

__device__ __forceinline__ short f2bf(float x) {
  uint32_t u = __builtin_bit_cast(uint32_t, x);
  u += 0x7fffu + ((u >> 16) & 1u);
  return (short)(u >> 16);
}

// ---------------- cast X: f32 -> bf16, 8 elems/thread ----------------
__global__ __launch_bounds__(256) void cast_x_kernel(const float* __restrict__ src,
                                                     short* __restrict__ dst) {
  const size_t i = (size_t)blockIdx.x * 256 + threadIdx.x;
  const float* s = src + i * 8;
  f32x4 a = *(const f32x4*)(s);
  f32x4 b = *(const f32x4*)(s + 4);
  s16x8 o;
  o[0] = f2bf(a[0]); o[1] = f2bf(a[1]); o[2] = f2bf(a[2]); o[3] = f2bf(a[3]);
  o[4] = f2bf(b[0]); o[5] = f2bf(b[1]); o[6] = f2bf(b[2]); o[7] = f2bf(b[3]);
  *(s16x8*)(dst + i * 8) = o;
}

// ------ transpose-cast: W[k][n] f32 -> Wt[n][k] bf16 (1024x1024) ------
__global__ __launch_bounds__(256) void transpose_cast_kernel(const float* __restrict__ src,
                                                             short* __restrict__ dst) {
  __shared__ float t[32][33];
  const int tx = threadIdx.x & 31, ty = threadIdx.x >> 5;
  const int r0 = blockIdx.y * 32, c0 = blockIdx.x * 32;
#pragma unroll
  for (int i = 0; i < 4; i++)
    t[ty + i * 8][tx] = src[(size_t)(r0 + ty + i * 8) * HID + c0 + tx];
  __syncthreads();
#pragma unroll
  for (int i = 0; i < 4; i++)
    dst[(size_t)(c0 + ty + i * 8) * HID + r0 + tx] = f2bf(t[tx][ty + i * 8]);
}

// ---------------- bf16 GEMM: C = A[M][1024] * Bt[N][1024]^T ----------------
// 128x128 tile, BK=32, 4 waves (2x2), 16x16x32 MFMA, global_load_lds staging.
// EPI 0: QKV epilogue (bias + scatter to Qb/Kb [bh][s][d], Vt [bh][d][s_perm])
// EPI 1: proj epilogue (bias + f32 out [m][1024])
template <int EPI>
__global__ __launch_bounds__(256) void gemm_bf16(
    const short* __restrict__ A, const short* __restrict__ Bt,
    const float* __restrict__ b0, const float* __restrict__ b1,
    const float* __restrict__ b2, short* __restrict__ Qb, short* __restrict__ Kb,
    short* __restrict__ Vt, float* __restrict__ Out) {
  __shared__ char lds[16384];  // A tile [128][32] @0, B tile [128][32] @8192
  const int tid = threadIdx.x;
  const int w = tid >> 6, l = tid & 63, lg = l >> 4, ln = l & 15;
  const int wm = w >> 1, wn = w & 1;
  const int m0 = blockIdx.y * 128, n0 = blockIdx.x * 128;

  f32x4 acc[4][4];
#pragma unroll
  for (int i = 0; i < 4; i++)
#pragma unroll
    for (int j = 0; j < 4; j++) acc[i][j] = f32x4{0.f, 0.f, 0.f, 0.f};

  for (int k0 = 0; k0 < 1024; k0 += 32) {
    __syncthreads();  // protect LDS from prior-iter readers
#pragma unroll
    for (int i = 0; i < 2; i++) {
      const int chunk = (w * 2 + i) * 64 + l;  // 16B chunk id, 4 chunks/row
      const int row = chunk >> 2;
      const int cs = (chunk & 3) ^ (row & 3);  // source-side XOR swizzle
      GLOAD_LDS16(A + (size_t)(m0 + row) * 1024 + k0 + cs * 8,
                  lds + (w * 2 + i) * 1024);
      GLOAD_LDS16(Bt + (size_t)(n0 + row) * 1024 + k0 + cs * 8,
                  lds + 8192 + (w * 2 + i) * 1024);
    }
    __syncthreads();  // compiler emits vmcnt(0) before barrier

    s16x8 af[4], bfr[4];
#pragma unroll
    for (int mi = 0; mi < 4; mi++) {
      const int row = wm * 64 + mi * 16 + ln;
      af[mi] = *(const s16x8*)(lds + row * 64 + ((lg ^ (row & 3)) * 16));
    }
#pragma unroll
    for (int ni = 0; ni < 4; ni++) {
      const int row = wn * 64 + ni * 16 + ln;
      bfr[ni] = *(const s16x8*)(lds + 8192 + row * 64 + ((lg ^ (row & 3)) * 16));
    }
#pragma unroll
    for (int mi = 0; mi < 4; mi++)
#pragma unroll
      for (int ni = 0; ni < 4; ni++)
        acc[mi][ni] = MFMA16(af[mi], bfr[ni], acc[mi][ni]);
  }

  // epilogue: C/D layout row=(lane>>4)*4+reg, col=lane&15
#pragma unroll
  for (int ni = 0; ni < 4; ni++) {
    const int c = n0 + wn * 64 + ni * 16 + ln;
    if (EPI == 0) {
      const int mat = c >> 10, cc = c & 1023, hh = cc >> 6, d = cc & 63;
      const float* bp = (mat == 0) ? b0 : (mat == 1) ? b1 : b2;
      const float bias = bp[cc];
#pragma unroll
      for (int mi = 0; mi < 4; mi++) {
#pragma unroll
        for (int r = 0; r < 4; r++) {
          const int m = m0 + wm * 64 + mi * 16 + lg * 4 + r;
          const int bb = m >> 11, s = m & 2047;
          const short v = f2bf(acc[mi][ni][r] + bias);
          const size_t bh = (size_t)(bb * 16 + hh);
          if (mat == 0)
            Qb[(bh * SEQ + s) * HD + d] = v;
          else if (mat == 1)
            Kb[(bh * SEQ + s) * HD + d] = v;
          else {
            // kappa-permute s within its 32-group so attn PV loads are 16B:
            // slot = ((s&15)>>2)*8 + ((s>>4)&1)*4 + (s&3)
            const int sp = (s & ~31) | ((s & 12) << 1) | (((s >> 4) & 1) << 2) |
                           (s & 3);
            Vt[(bh * HD + d) * SEQ + sp] = v;
          }
        }
      }
    } else {
      const float bias = b0[c];
#pragma unroll
      for (int mi = 0; mi < 4; mi++)
#pragma unroll
        for (int r = 0; r < 4; r++) {
          const int m = m0 + wm * 64 + mi * 16 + lg * 4 + r;
          Out[(size_t)m * 1024 + c] = acc[mi][ni][r] + bias;
        }
    }
  }
}

// ---------------- flash attention (causal), LDS-free, wave-paired ----------------
// 2048 waves total; wave handles query row-blocks rb and 127-rb (33 tile-units
// each, perfectly balanced). S^T = mfma(K,Q): lane owns query col q=ln; softmax
// per-lane; P feeds PV B-operand with no cross-lane movement. K(kt+1)/V(kt)
// loads issued before softmax so their latency hides under the exp chain.

__device__ __forceinline__ void load_ktile(const short* Kbase, int k0, int ln,
                                           int lg, s16x8 kf[4][2]) {
#pragma unroll
  for (int mt = 0; mt < 4; mt++) {
    const short* Kp = Kbase + (size_t)(k0 + mt * 16 + ln) * HD + lg * 8;
    kf[mt][0] = *(const s16x8*)(Kp);
    kf[mt][1] = *(const s16x8*)(Kp + 32);
  }
}

__device__ __forceinline__ void load_vtile(const short* Vbase, int k0, int ln,
                                           int lg, s16x8 vf[2][4]) {
#pragma unroll
  for (int s = 0; s < 2; s++)
#pragma unroll
    for (int vmt = 0; vmt < 4; vmt++) {
      // V stored kappa-permuted: one contiguous 16B load per fragment
      const short* Vp = Vbase + (size_t)(vmt * 16 + ln) * SEQ + k0 + s * 32 + lg * 8;
      vf[s][vmt] = *(const s16x8*)(Vp);
    }
}

template <bool MASK>
__device__ __forceinline__ void softmax_pv(f32x4 st[4], const s16x8 vf[2][4],
                                           f32x4 o[4], float& m2, float& l_run,
                                           int k0, int qrow, int lg) {
  const float SC = 0.18033688011112042f;  // (1/8) * log2(e)
  float p[4][4];
  float pmax = -3e38f;
#pragma unroll
  for (int mt = 0; mt < 4; mt++)
#pragma unroll
    for (int r = 0; r < 4; r++) {
      float v = st[mt][r] * SC;
      if (MASK) {
        const int key = k0 + mt * 16 + lg * 4 + r;
        if (key > qrow) v = -3e38f;
      }
      p[mt][r] = v;
      pmax = fmaxf(pmax, v);
    }
  pmax = fmaxf(pmax, __shfl_xor(pmax, 16));
  pmax = fmaxf(pmax, __shfl_xor(pmax, 32));
  const float m_new = fmaxf(m2, pmax);
  const float corr = exp2f(m2 - m_new);
  float psum = 0.f;
#pragma unroll
  for (int mt = 0; mt < 4; mt++)
#pragma unroll
    for (int r = 0; r < 4; r++) {
      const float e = exp2f(p[mt][r] - m_new);
      p[mt][r] = e;
      psum += e;
    }
  psum += __shfl_xor(psum, 16);
  psum += __shfl_xor(psum, 32);
  l_run = l_run * corr + psum;
  m2 = m_new;
#pragma unroll
  for (int i = 0; i < 4; i++) o[i] *= corr;

  s16x8 pf[2];
#pragma unroll
  for (int s = 0; s < 2; s++)
#pragma unroll
    for (int h = 0; h < 2; h++)
#pragma unroll
      for (int r = 0; r < 4; r++) pf[s][h * 4 + r] = f2bf(p[s * 2 + h][r]);
#pragma unroll
  for (int s = 0; s < 2; s++)
#pragma unroll
    for (int vmt = 0; vmt < 4; vmt++)
      o[vmt] = MFMA16(vf[s][vmt], pf[s], o[vmt]);
}

__device__ __forceinline__ void flash_pass(const short* __restrict__ Qb,
                                           const short* Kbase,
                                           const short* Vbase,
                                           short* __restrict__ Ob, int bh,
                                           int rb, int l) {
  const int lg = l >> 4, ln = l & 15;
  const int qrow = rb * 16 + ln;
  const short* Qp = Qb + ((size_t)bh * SEQ + qrow) * HD;
  const s16x8 qf0 = *(const s16x8*)(Qp + lg * 8);
  const s16x8 qf1 = *(const s16x8*)(Qp + 32 + lg * 8);

  float m2 = -3e38f, l_run = 0.f;
  f32x4 o[4];
#pragma unroll
  for (int i = 0; i < 4; i++) o[i] = f32x4{0.f, 0.f, 0.f, 0.f};

  const int nfull = rb >> 2;  // tiles 0..nfull-1 are fully unmasked
  s16x8 kcur[4][2];
  load_ktile(Kbase, 0, ln, lg, kcur);

  for (int kt = 0; kt < nfull; ++kt) {
    f32x4 st[4];
#pragma unroll
    for (int mt = 0; mt < 4; mt++) {
      st[mt] = f32x4{0.f, 0.f, 0.f, 0.f};
      st[mt] = MFMA16(kcur[mt][0], qf0, st[mt]);
      st[mt] = MFMA16(kcur[mt][1], qf1, st[mt]);
    }
    s16x8 knext[4][2];
    load_ktile(Kbase, (kt + 1) * 64, ln, lg, knext);  // prefetch next K
    s16x8 vf[2][4];
    load_vtile(Vbase, kt * 64, ln, lg, vf);  // issue V before softmax
    softmax_pv<false>(st, vf, o, m2, l_run, kt * 64, qrow, lg);
#pragma unroll
    for (int mt = 0; mt < 4; mt++) {
      kcur[mt][0] = knext[mt][0];
      kcur[mt][1] = knext[mt][1];
    }
  }
  {  // masked diagonal tile (kt == nfull), kcur already holds it
    f32x4 st[4];
#pragma unroll
    for (int mt = 0; mt < 4; mt++) {
      st[mt] = f32x4{0.f, 0.f, 0.f, 0.f};
      st[mt] = MFMA16(kcur[mt][0], qf0, st[mt]);
      st[mt] = MFMA16(kcur[mt][1], qf1, st[mt]);
    }
    s16x8 vf[2][4];
    load_vtile(Vbase, nfull * 64, ln, lg, vf);
    softmax_pv<true>(st, vf, o, m2, l_run, nfull * 64, qrow, lg);
  }

  const float inv = 1.0f / l_run;
  const int bb = bh >> 4, hh = bh & 15;
  const size_t orow = (size_t)(bb * SEQ + qrow) * HID + hh * HD;
#pragma unroll
  for (int mt = 0; mt < 4; mt++) {
    s16x4 ov;
#pragma unroll
    for (int r = 0; r < 4; r++) ov[r] = f2bf(o[mt][r] * inv);
    *(s16x4*)(Ob + orow + mt * 16 + lg * 4) = ov;
  }
}

__global__ __launch_bounds__(256) void attn_kernel(const short* __restrict__ Qb,
                                                   const short* __restrict__ Kb,
                                                   const short* __restrict__ Vt,
                                                   short* __restrict__ Ob) {
  const int bh = blockIdx.y;
  const int w = threadIdx.x >> 6, l = threadIdx.x & 63;
  const int pi = blockIdx.x * 4 + w;  // [0,64)
  const short* Kbase = Kb + (size_t)bh * (SEQ * HD);
  const short* Vbase = Vt + (size_t)bh * (HD * SEQ);
  flash_pass(Qb, Kbase, Vbase, Ob, bh, pi, l);        // short pass
  flash_pass(Qb, Kbase, Vbase, Ob, bh, 127 - pi, l);  // long pass
}

// ---------------- launch ----------------
extern "C" void kernel_launch(void* const* d_in, const int* in_sizes, int n_in,
                              void* d_out, int out_size, void* d_ws,
                              size_t ws_size, hipStream_t stream) {
  const float* X = (const float*)d_in[0];
  // d_in[1] = mask (causal, implemented directly)
  const float* Wq = (const float*)d_in[2];
  const float* bq = (const float*)d_in[3];
  const float* Wk = (const float*)d_in[4];
  const float* bk = (const float*)d_in[5];
  const float* Wv = (const float*)d_in[6];
  const float* Wo = (const float*)d_in[8];
  const float* bv = (const float*)d_in[7];
  const float* bo = (const float*)d_in[9];
  float* out = (float*)d_out;

  char* ws = (char*)d_ws;
  short* Xb = (short*)(ws);                    // 8 MB  [4096][1024]
  short* Wt = (short*)(ws + (8u << 20));       // 6 MB  [3072][1024] (Wq|Wk|Wv)^T
  short* Wto = (short*)(ws + (14u << 20));     // 2 MB  [1024][1024] Wo^T
  short* Qb = (short*)(ws + (16u << 20));      // 8 MB  [32][2048][64]
  short* Kb = (short*)(ws + (24u << 20));      // 8 MB
  short* Vt = (short*)(ws + (32u << 20));      // 8 MB  [32][64][2048] kappa-perm
  short* Ob = (short*)(ws + (40u << 20));      // 8 MB  [4096][1024]

  cast_x_kernel<<<2048, 256, 0, stream>>>(X, Xb);
  transpose_cast_kernel<<<dim3(32, 32), 256, 0, stream>>>(Wq, Wt);
  transpose_cast_kernel<<<dim3(32, 32), 256, 0, stream>>>(Wk, Wt + (1u << 20));
  transpose_cast_kernel<<<dim3(32, 32), 256, 0, stream>>>(Wv, Wt + (2u << 20));
  transpose_cast_kernel<<<dim3(32, 32), 256, 0, stream>>>(Wo, Wto);

  gemm_bf16<0><<<dim3(24, 32), 256, 0, stream>>>(Xb, Wt, bq, bk, bv, Qb, Kb, Vt,
                                                 nullptr);
  attn_kernel<<<dim3(16, 32), 256, 0, stream>>>(Qb, Kb, Vt, Ob);
  gemm_bf16<1><<<dim3(8, 32), 256, 0, stream>>>(Ob, Wto, bo, nullptr, nullptr,
                                                nullptr, nullptr, nullptr, out);
}